// Round 1
// baseline (347.277 us; speedup 1.0000x reference)
//
#include <hip/hip_runtime.h>
#include <stdint.h>

// ---------------------------------------------------------------------------
// Linear (kernelized) attention, B=4 L=4096 D=1024 H=16 M=64, fp32 in/out.
// Attention is a global sum over L -> two GEMM passes, no SxS matrix:
//   1. k_prep_w : transpose weights -> bf16 WT[out][in]  (MFMA B layout)
//   2. k_proj   : q = relu(X Wq + b)+eps -> q bf16 [B][L][1024]   (MODE 0)
//                 k -> kt bf16 [B][1024][L]  (transposed)         (MODE 1)
//                 v -> vt bf16 [B][16][80][L] rows 0..63          (MODE 2)
//      k_init_vt: vt row 64 = 1.0 (so kvs GEMM col 64 = ks_sum), 65..79 = 0
//   3. k_kvs    : per (b,h): kvs[64 m][80 d'] += kt . vt^T over l (fp32 atomics)
//   4. k_kvs_t  : kvs fp32 -> bav bf16 [b][h][80 d'][64 m]   (transpose)
//   5. k_av     : per (b,h): C[l][80] = q . bav^T; col 64 = norm;
//                 avn[l][hm] = C/norm  (bf16)
//   6. k_out    : out = avn . WoT + bo   (fp32)
// All GEMMs: mfma_f32_16x16x32_bf16, fp32 accum, reg-staged LDS (round 1:
// no global_load_lds / no swizzle yet -- correctness + baseline counters).
// ---------------------------------------------------------------------------

typedef __bf16 bf16;
typedef __bf16 bf16x4 __attribute__((ext_vector_type(4)));
typedef __bf16 bf16x8 __attribute__((ext_vector_type(8)));
typedef float f32x4 __attribute__((ext_vector_type(4)));

#define MFMA_(a, b, c) __builtin_amdgcn_mfma_f32_16x16x32_bf16((a), (b), (c), 0, 0, 0)

static constexpr int BB   = 4;
static constexpr int LSEQ = 4096;
static constexpr int DIM  = 1024;   // D == H*M
static constexpr int HH   = 16;
static constexpr float EPSF = 0.001f;

// ---------------- weight transpose: fp32 [1024][1024] -> bf16 out[c][r] ----
__global__ void k_prep_w(const float* __restrict__ W, bf16* __restrict__ WT) {
  __shared__ float t[32][33];
  const int tx = threadIdx.x & 31, ty = threadIdx.x >> 5;   // 32 x 8
  const int r0 = blockIdx.x * 32, c0 = blockIdx.y * 32;
#pragma unroll
  for (int j = 0; j < 32; j += 8)
    t[ty + j][tx] = W[(size_t)(r0 + ty + j) * DIM + c0 + tx];
  __syncthreads();
#pragma unroll
  for (int j = 0; j < 32; j += 8)
    WT[(size_t)(c0 + ty + j) * DIM + r0 + tx] = (bf16)t[tx][ty + j];
}

// ---------------- vt rows 64..79: row 64 = ones, rest zeros ----------------
__global__ void k_init_vt(bf16* __restrict__ vt) {
  const int idx = blockIdx.x * 256 + threadIdx.x;  // B*H*16*L = 4,194,304
  const int l  = idx & (LSEQ - 1);
  const int r  = (idx >> 12) & 15;
  const int bh = idx >> 16;
  if (bh < BB * HH)
    vt[((size_t)bh * 80 + 64 + r) * LSEQ + l] = (r == 0) ? (bf16)1.0f : (bf16)0.0f;
}

// ---------------- projection GEMM: C = act(X . WT^T + bias) ----------------
// MODE 0: q  -> out[n][c]                     (relu + eps)
// MODE 1: k  -> out[(b*1024 + c)][l]          (relu + eps, transposed)
// MODE 2: v  -> out[((b*16+h)*80 + d)][l]     (no act, transposed)
template <int MODE>
__global__ __launch_bounds__(256, 2) void k_proj(const float* __restrict__ X,
                                                 const bf16* __restrict__ WT,
                                                 const float* __restrict__ bias,
                                                 bf16* __restrict__ out) {
  __shared__ bf16 As[128][64];   // X tile (fp32 -> bf16 reg-staged)
  __shared__ bf16 Bs[128][64];   // WT tile
  const int tid = threadIdx.x;
  const int lane = tid & 63, wid = tid >> 6;
  const int wr = wid >> 1, wc = wid & 1;
  const int lr = lane & 15, lk = lane >> 4;
  const int n0 = blockIdx.x * 128;
  const int c0 = blockIdx.y * 128;
  f32x4 acc[4][4] = {};

  for (int ks = 0; ks < 16; ++ks) {
    const int k0 = ks * 64;
    __syncthreads();
    // stage A (128x64 fp32 -> bf16): 8 x float4 per thread
    float4 av[8];
#pragma unroll
    for (int i = 0; i < 8; ++i) {
      const int f = i * 1024 + tid * 4;
      const int row = f >> 6, col = f & 63;
      av[i] = *reinterpret_cast<const float4*>(X + (size_t)(n0 + row) * DIM + k0 + col);
    }
#pragma unroll
    for (int i = 0; i < 8; ++i) {
      const int f = i * 1024 + tid * 4;
      const int row = f >> 6, col = f & 63;
      bf16x4 p;
      p[0] = (bf16)av[i].x; p[1] = (bf16)av[i].y;
      p[2] = (bf16)av[i].z; p[3] = (bf16)av[i].w;
      *reinterpret_cast<bf16x4*>(&As[row][col]) = p;
    }
    // stage B (128x64 bf16): 4 x bf16x8 per thread
#pragma unroll
    for (int i = 0; i < 4; ++i) {
      const int e = i * 2048 + tid * 8;
      const int row = e >> 6, col = e & 63;
      *reinterpret_cast<bf16x8*>(&Bs[row][col]) =
          *reinterpret_cast<const bf16x8*>(WT + (size_t)(c0 + row) * DIM + k0 + col);
    }
    __syncthreads();
#pragma unroll
    for (int kk = 0; kk < 2; ++kk) {
      bf16x8 af[4], bfr[4];
#pragma unroll
      for (int rb = 0; rb < 4; ++rb)
        af[rb] = *reinterpret_cast<const bf16x8*>(&As[wr * 64 + rb * 16 + lr][kk * 32 + lk * 8]);
#pragma unroll
      for (int cb = 0; cb < 4; ++cb)
        bfr[cb] = *reinterpret_cast<const bf16x8*>(&Bs[wc * 64 + cb * 16 + lr][kk * 32 + lk * 8]);
#pragma unroll
      for (int rb = 0; rb < 4; ++rb)
#pragma unroll
        for (int cb = 0; cb < 4; ++cb)
          acc[rb][cb] = MFMA_(af[rb], bfr[cb], acc[rb][cb]);
    }
  }

  // epilogue
  float bvv[4];
#pragma unroll
  for (int cb = 0; cb < 4; ++cb) bvv[cb] = bias[c0 + wc * 64 + cb * 16 + lr];
  const int bidx = n0 >> 12;           // batch
  const int l0 = n0 & (LSEQ - 1);
#pragma unroll
  for (int rb = 0; rb < 4; ++rb) {
#pragma unroll
    for (int cb = 0; cb < 4; ++cb) {
      const int c = c0 + wc * 64 + cb * 16 + lr;
      if (MODE == 0) {
#pragma unroll
        for (int r = 0; r < 4; ++r) {
          float x = acc[rb][cb][r] + bvv[cb];
          x = fmaxf(x, 0.f) + EPSF;
          const int row = n0 + wr * 64 + rb * 16 + lk * 4 + r;
          out[(size_t)row * DIM + c] = (bf16)x;
        }
      } else {
        const int l = l0 + wr * 64 + rb * 16 + lk * 4;
        bf16x4 o;
#pragma unroll
        for (int r = 0; r < 4; ++r) {
          float x = acc[rb][cb][r] + bvv[cb];
          if (MODE == 1) x = fmaxf(x, 0.f) + EPSF;
          o[r] = (bf16)x;
        }
        size_t rowbase;
        if (MODE == 1) rowbase = (size_t)bidx * 1024 + c;                       // kt [b][c][L]
        else           rowbase = ((size_t)(bidx * HH + (c >> 6)) * 80 + (c & 63)); // vt [b][h][80][L]
        *reinterpret_cast<bf16x4*>(out + rowbase * LSEQ + l) = o;
      }
    }
  }
}

// ---------------- kvs: per (b,h) C[64 m][80 d'] = kt . vt^T over l ---------
__global__ __launch_bounds__(256, 2) void k_kvs(const bf16* __restrict__ kt,
                                                const bf16* __restrict__ vt,
                                                float* __restrict__ kvs) {
  const int tid = threadIdx.x, lane = tid & 63, wid = tid >> 6;
  const int lr = lane & 15, lk = lane >> 4;
  const int bh = blockIdx.y;
  const int lbase = blockIdx.x * 1024;
  __shared__ bf16 As[64][64];   // kt tile
  __shared__ bf16 Bs[80][64];   // vt tile (incl ones row)
  f32x4 acc[5] = {};
  const bf16* ktb = kt + (size_t)bh * 64 * LSEQ;
  const bf16* vtb = vt + (size_t)bh * 80 * LSEQ;

  for (int ks = 0; ks < 16; ++ks) {
    const int l0 = lbase + ks * 64;
    __syncthreads();
#pragma unroll
    for (int i = 0; i < 2; ++i) {   // A: 4096 elems
      const int e = i * 2048 + tid * 8;
      const int row = e >> 6, col = e & 63;
      *reinterpret_cast<bf16x8*>(&As[row][col]) =
          *reinterpret_cast<const bf16x8*>(ktb + (size_t)row * LSEQ + l0 + col);
    }
#pragma unroll
    for (int i = 0; i < 2; ++i) {   // B: first 4096 of 5120
      const int e = i * 2048 + tid * 8;
      const int row = e >> 6, col = e & 63;
      *reinterpret_cast<bf16x8*>(&Bs[row][col]) =
          *reinterpret_cast<const bf16x8*>(vtb + (size_t)row * LSEQ + l0 + col);
    }
    if (tid < 128) {                // B: rows 64..79
      const int e = 4096 + tid * 8;
      const int row = e >> 6, col = e & 63;
      *reinterpret_cast<bf16x8*>(&Bs[row][col]) =
          *reinterpret_cast<const bf16x8*>(vtb + (size_t)row * LSEQ + l0 + col);
    }
    __syncthreads();
#pragma unroll
    for (int kk = 0; kk < 2; ++kk) {
      const bf16x8 af = *reinterpret_cast<const bf16x8*>(&As[wid * 16 + lr][kk * 32 + lk * 8]);
#pragma unroll
      for (int cb = 0; cb < 5; ++cb) {
        const bf16x8 bfr = *reinterpret_cast<const bf16x8*>(&Bs[cb * 16 + lr][kk * 32 + lk * 8]);
        acc[cb] = MFMA_(af, bfr, acc[cb]);
      }
    }
  }
  float* kb = kvs + (size_t)bh * 64 * 80;
#pragma unroll
  for (int cb = 0; cb < 5; ++cb) {
    const int dcol = cb * 16 + lr;
#pragma unroll
    for (int r = 0; r < 4; ++r) {
      const int m = wid * 16 + lk * 4 + r;
      atomicAdd(kb + m * 80 + dcol, acc[cb][r]);
    }
  }
}

// ---------------- kvs fp32 [bh][64][80] -> bav bf16 [bh][80][64] -----------
__global__ void k_kvs_t(const float* __restrict__ kvs, bf16* __restrict__ bav) {
  const int bh = blockIdx.x;
  const float* src = kvs + (size_t)bh * 5120;
  bf16* dst = bav + (size_t)bh * 5120;
  for (int i = threadIdx.x; i < 5120; i += 256) {
    const int dp = i >> 6, mm = i & 63;
    dst[i] = (bf16)src[mm * 80 + dp];
  }
}

// ---------------- av: per (b,h) C[128 l][80] = q . bav^T; normalize --------
__global__ __launch_bounds__(256, 2) void k_av(const bf16* __restrict__ q,
                                               const bf16* __restrict__ bav,
                                               bf16* __restrict__ avn) {
  const int tid = threadIdx.x, lane = tid & 63, wid = tid >> 6;
  const int lr = lane & 15, lk = lane >> 4;
  const int bh = blockIdx.y, b = bh >> 4, h = bh & 15;
  const int l0 = blockIdx.x * 128;
  __shared__ bf16 As[128][64];
  __shared__ bf16 Bs[80][64];
  __shared__ float nrm[128];

  const bf16* qb = q + ((size_t)b * LSEQ + l0) * DIM + h * 64;
#pragma unroll
  for (int i = 0; i < 4; ++i) {
    const int e = i * 2048 + tid * 8;
    const int row = e >> 6, col = e & 63;
    *reinterpret_cast<bf16x8*>(&As[row][col]) =
        *reinterpret_cast<const bf16x8*>(qb + (size_t)row * DIM + col);
  }
  const bf16* bb = bav + (size_t)bh * 5120;
#pragma unroll
  for (int i = 0; i < 2; ++i) {
    const int e = i * 2048 + tid * 8;
    const int row = e >> 6, col = e & 63;
    *reinterpret_cast<bf16x8*>(&Bs[row][col]) =
        *reinterpret_cast<const bf16x8*>(bb + row * 64 + col);
  }
  if (tid < 128) {
    const int e = 4096 + tid * 8;
    const int row = e >> 6, col = e & 63;
    *reinterpret_cast<bf16x8*>(&Bs[row][col]) =
        *reinterpret_cast<const bf16x8*>(bb + row * 64 + col);
  }
  __syncthreads();

  f32x4 acc[2][5] = {};
#pragma unroll
  for (int kk = 0; kk < 2; ++kk) {
    bf16x8 af[2];
    af[0] = *reinterpret_cast<const bf16x8*>(&As[wid * 32 + lr][kk * 32 + lk * 8]);
    af[1] = *reinterpret_cast<const bf16x8*>(&As[wid * 32 + 16 + lr][kk * 32 + lk * 8]);
#pragma unroll
    for (int cb = 0; cb < 5; ++cb) {
      const bf16x8 bfr = *reinterpret_cast<const bf16x8*>(&Bs[cb * 16 + lr][kk * 32 + lk * 8]);
      acc[0][cb] = MFMA_(af[0], bfr, acc[0][cb]);
      acc[1][cb] = MFMA_(af[1], bfr, acc[1][cb]);
    }
  }
  if (lr == 0) {
#pragma unroll
    for (int rb = 0; rb < 2; ++rb)
#pragma unroll
      for (int r = 0; r < 4; ++r)
        nrm[wid * 32 + rb * 16 + lk * 4 + r] = acc[rb][4][r];
  }
  __syncthreads();
  bf16* ob = avn + ((size_t)b * LSEQ + l0) * DIM + h * 64;
#pragma unroll
  for (int rb = 0; rb < 2; ++rb) {
#pragma unroll
    for (int cb = 0; cb < 4; ++cb) {
#pragma unroll
      for (int r = 0; r < 4; ++r) {
        const int row = wid * 32 + rb * 16 + lk * 4 + r;
        const float x = acc[rb][cb][r] / nrm[row];
        ob[(size_t)row * DIM + cb * 16 + lr] = (bf16)x;
      }
    }
  }
}

// ---------------- out: out = avn . WoT^T + bo   (fp32) ---------------------
__global__ __launch_bounds__(256, 2) void k_out(const bf16* __restrict__ A,
                                                const bf16* __restrict__ WoT,
                                                const float* __restrict__ bo,
                                                float* __restrict__ out) {
  __shared__ bf16 As[128][64], Bs[128][64];
  const int tid = threadIdx.x, lane = tid & 63, wid = tid >> 6;
  const int wr = wid >> 1, wc = wid & 1;
  const int lr = lane & 15, lk = lane >> 4;
  const int n0 = blockIdx.x * 128, c0 = blockIdx.y * 128;
  f32x4 acc[4][4] = {};

  for (int ks = 0; ks < 16; ++ks) {
    const int k0 = ks * 64;
    __syncthreads();
#pragma unroll
    for (int i = 0; i < 4; ++i) {
      const int e = i * 2048 + tid * 8;
      const int row = e >> 6, col = e & 63;
      *reinterpret_cast<bf16x8*>(&As[row][col]) =
          *reinterpret_cast<const bf16x8*>(A + (size_t)(n0 + row) * DIM + k0 + col);
    }
#pragma unroll
    for (int i = 0; i < 4; ++i) {
      const int e = i * 2048 + tid * 8;
      const int row = e >> 6, col = e & 63;
      *reinterpret_cast<bf16x8*>(&Bs[row][col]) =
          *reinterpret_cast<const bf16x8*>(WoT + (size_t)(c0 + row) * DIM + k0 + col);
    }
    __syncthreads();
#pragma unroll
    for (int kk = 0; kk < 2; ++kk) {
      bf16x8 af[4], bfr[4];
#pragma unroll
      for (int rb = 0; rb < 4; ++rb)
        af[rb] = *reinterpret_cast<const bf16x8*>(&As[wr * 64 + rb * 16 + lr][kk * 32 + lk * 8]);
#pragma unroll
      for (int cb = 0; cb < 4; ++cb)
        bfr[cb] = *reinterpret_cast<const bf16x8*>(&Bs[wc * 64 + cb * 16 + lr][kk * 32 + lk * 8]);
#pragma unroll
      for (int rb = 0; rb < 4; ++rb)
#pragma unroll
        for (int cb = 0; cb < 4; ++cb)
          acc[rb][cb] = MFMA_(af[rb], bfr[cb], acc[rb][cb]);
    }
  }
  float bvv[4];
#pragma unroll
  for (int cb = 0; cb < 4; ++cb) bvv[cb] = bo[c0 + wc * 64 + cb * 16 + lr];
#pragma unroll
  for (int rb = 0; rb < 4; ++rb)
#pragma unroll
    for (int cb = 0; cb < 4; ++cb)
#pragma unroll
      for (int r = 0; r < 4; ++r) {
        const int row = n0 + wr * 64 + rb * 16 + lk * 4 + r;
        const int c = c0 + wc * 64 + cb * 16 + lr;
        out[(size_t)row * DIM + c] = acc[rb][cb][r] + bvv[cb];
      }
}

// ---------------------------------------------------------------------------
extern "C" void kernel_launch(void* const* d_in, const int* in_sizes, int n_in,
                              void* d_out, int out_size, void* d_ws, size_t ws_size,
                              hipStream_t stream) {
  const float* query = (const float*)d_in[0];
  const float* key   = (const float*)d_in[1];
  const float* value = (const float*)d_in[2];
  const float* Wq    = (const float*)d_in[3];
  const float* bq    = (const float*)d_in[4];
  const float* Wk    = (const float*)d_in[5];
  const float* bk    = (const float*)d_in[6];
  const float* Wv    = (const float*)d_in[7];
  const float* bvp   = (const float*)d_in[8];
  const float* Wo    = (const float*)d_in[9];
  const float* bo    = (const float*)d_in[10];
  float* out = (float*)d_out;
  char* ws = (char*)d_ws;

  // workspace layout (bytes)
  const size_t off_wqt = 0;                       // 2 MB each
  const size_t off_wkt = off_wqt + (2u << 20);
  const size_t off_wvt = off_wkt + (2u << 20);
  const size_t off_wot = off_wvt + (2u << 20);
  const size_t off_q   = off_wot + (2u << 20);    // 33,554,432
  const size_t off_kt  = off_q   + 33554432ull;
  const size_t off_vt  = off_kt  + 33554432ull;   // 41,943,040
  const size_t off_av  = off_vt  + 41943040ull;
  const size_t off_kvs = off_av  + 33554432ull;   // 1,310,720 (fp32)
  const size_t off_bav = off_kvs + 1310720ull;    //   655,360
  const size_t total   = off_bav + 655360ull;     // ~146 MB
  if (ws_size < total) return;

  bf16*  WQT = (bf16*)(ws + off_wqt);
  bf16*  WKT = (bf16*)(ws + off_wkt);
  bf16*  WVT = (bf16*)(ws + off_wvt);
  bf16*  WOT = (bf16*)(ws + off_wot);
  bf16*  Qb  = (bf16*)(ws + off_q);
  bf16*  KT  = (bf16*)(ws + off_kt);
  bf16*  VT  = (bf16*)(ws + off_vt);
  bf16*  AV  = (bf16*)(ws + off_av);
  float* KVS = (float*)(ws + off_kvs);
  bf16*  BAV = (bf16*)(ws + off_bav);

  // prep
  k_prep_w<<<dim3(32, 32), 256, 0, stream>>>(Wq, WQT);
  k_prep_w<<<dim3(32, 32), 256, 0, stream>>>(Wk, WKT);
  k_prep_w<<<dim3(32, 32), 256, 0, stream>>>(Wv, WVT);
  k_prep_w<<<dim3(32, 32), 256, 0, stream>>>(Wo, WOT);
  k_init_vt<<<16384, 256, 0, stream>>>(VT);
  hipMemsetAsync(KVS, 0, 1310720ull, stream);

  // projections (grid: 16384/128 row tiles x 1024/128 col tiles)
  k_proj<0><<<dim3(128, 8), 256, 0, stream>>>(query, WQT, bq, Qb);
  k_proj<1><<<dim3(128, 8), 256, 0, stream>>>(key,   WKT, bk, KT);
  k_proj<2><<<dim3(128, 8), 256, 0, stream>>>(value, WVT, bvp, VT);

  // state + normalizer
  k_kvs<<<dim3(4, 64), 256, 0, stream>>>(KT, VT, KVS);
  k_kvs_t<<<64, 256, 0, stream>>>(KVS, BAV);

  // attention readout + normalization
  k_av<<<dim3(32, 64), 256, 0, stream>>>(Qb, BAV, AV);

  // output projection
  k_out<<<dim3(128, 8), 256, 0, stream>>>(AV, WOT, bo, out);
}

// Round 2
// 284.584 us; speedup vs baseline: 1.2203x; 1.2203x over previous
//
#include <hip/hip_runtime.h>
#include <stdint.h>

// ---------------------------------------------------------------------------
// Linear (kernelized) attention, B=4 L=4096 D=1024 H=16 M=64, fp32 in/out.
//   1. k_cvt    : q/k/v fp32 -> bf16 XB[3][16384][1024]  (vectorized, HBM-bound)
//   2. k_prep_w4: 4 weight transposes -> bf16 WT[out][in] (MFMA B layout)
//   3. k_proj   : m97-style 128x128/BK=64 MFMA GEMM, global_load_lds x16 both
//                 operands.  MODE 0: q=relu(X Wq+b)+eps -> [B][L][1024]
//                 MODE 1: k -> kt [B][1024][L] (transposed)
//                 MODE 2: v -> vt [B][16][80][L] rows 0..63
//      k_init_vt: vt row 64 = 1.0 (kvs col 64 = ks_sum), 65..79 = 0
//   4. k_kvs    : per (b,h) kvs[64 m][80 d'] += kt . vt^T  (fp32 atomics)
//   5. k_kvs_t  : kvs fp32 -> bav bf16 [bh][80][64] (transpose)
//   6. k_av     : C[l][80] = q . bav^T; col 64 = norm; avn = C/norm (bf16)
//   7. k_out    : out = avn . WoT + bo (fp32), m97-style GEMM
// Workspace aliasing: projections run v->k->q; KT=XBv, Qb=XBk, AV=XBq.
// ---------------------------------------------------------------------------

typedef __bf16 bf16;
typedef __bf16 bf16x4 __attribute__((ext_vector_type(4)));
typedef __bf16 bf16x8 __attribute__((ext_vector_type(8)));
typedef float f32x4 __attribute__((ext_vector_type(4)));

#define MFMA_(a, b, c) __builtin_amdgcn_mfma_f32_16x16x32_bf16((a), (b), (c), 0, 0, 0)

static constexpr int BB   = 4;
static constexpr int LSEQ = 4096;
static constexpr int DIM  = 1024;   // D == H*M
static constexpr int HH   = 16;
static constexpr float EPSF = 0.001f;

// ---- async global->LDS, 16B per lane, wave-uniform LDS base ---------------
__device__ __forceinline__ void gload16(bf16* lds, const bf16* g) {
  __builtin_amdgcn_global_load_lds(
      (const __attribute__((address_space(1))) void*)g,
      (__attribute__((address_space(3))) void*)lds, 16, 0, 0);
}

// stage a 128x64 bf16 tile from row-major src (pre-offset to tile origin).
// 4 waves x 4 chunks x (64 lanes x 16B) = 32 KB ... (16 KB bf16 = 8192 elems)
__device__ __forceinline__ void stage128(bf16* lds, const bf16* src, size_t ld,
                                         int wid, int lane) {
#pragma unroll
  for (int j = 0; j < 4; ++j) {
    const int chunk = wid * 4 + j;
    const int e = chunk * 512 + lane * 8;
    gload16(lds + chunk * 512, src + (size_t)(e >> 6) * ld + (e & 63));
  }
}

// ---------------- q/k/v fp32 -> bf16 ---------------------------------------
__global__ void k_cvt(const float* __restrict__ q, const float* __restrict__ k,
                      const float* __restrict__ v, bf16* __restrict__ xb) {
  const int which = blockIdx.y;
  const float* src = which == 0 ? q : (which == 1 ? k : v);
  bf16* dst = xb + (size_t)which * 16777216u;
  const size_t i = ((size_t)blockIdx.x * 256 + threadIdx.x) * 8;
  const float4 a = *reinterpret_cast<const float4*>(src + i);
  const float4 b = *reinterpret_cast<const float4*>(src + i + 4);
  bf16x8 o;
  o[0] = (bf16)a.x; o[1] = (bf16)a.y; o[2] = (bf16)a.z; o[3] = (bf16)a.w;
  o[4] = (bf16)b.x; o[5] = (bf16)b.y; o[6] = (bf16)b.z; o[7] = (bf16)b.w;
  *reinterpret_cast<bf16x8*>(dst + i) = o;
}

// ---------------- weight transpose: fp32 [1024][1024] -> bf16 out[c][r] ----
__global__ void k_prep_w4(const float* __restrict__ W0, const float* __restrict__ W1,
                          const float* __restrict__ W2, const float* __restrict__ W3,
                          bf16* __restrict__ T0, bf16* __restrict__ T1,
                          bf16* __restrict__ T2, bf16* __restrict__ T3) {
  const float* W; bf16* T;
  switch (blockIdx.z) {
    case 0:  W = W0; T = T0; break;
    case 1:  W = W1; T = T1; break;
    case 2:  W = W2; T = T2; break;
    default: W = W3; T = T3; break;
  }
  __shared__ float t[32][33];
  const int tx = threadIdx.x & 31, ty = threadIdx.x >> 5;   // 32 x 8
  const int r0 = blockIdx.x * 32, c0 = blockIdx.y * 32;
#pragma unroll
  for (int j = 0; j < 32; j += 8)
    t[ty + j][tx] = W[(size_t)(r0 + ty + j) * DIM + c0 + tx];
  __syncthreads();
#pragma unroll
  for (int j = 0; j < 32; j += 8)
    T[(size_t)(c0 + ty + j) * DIM + r0 + tx] = (bf16)t[tx][ty + j];
}

// ---------------- vt rows 64..79: row 64 = ones, rest zeros ----------------
__global__ void k_init_vt(bf16* __restrict__ vt) {
  const int idx = blockIdx.x * 256 + threadIdx.x;  // B*H*16*L = 4,194,304
  const int l  = idx & (LSEQ - 1);
  const int r  = (idx >> 12) & 15;
  const int bh = idx >> 16;
  if (bh < BB * HH)
    vt[((size_t)bh * 80 + 64 + r) * LSEQ + l] = (r == 0) ? (bf16)1.0f : (bf16)0.0f;
}

// ---------------- projection GEMM: C = act(X . WT^T + bias) ----------------
// MODE 0: q  -> out[n][c]                     (relu + eps)
// MODE 1: k  -> out[(b*1024 + c)][l]          (relu + eps, transposed)
// MODE 2: v  -> out[((b*16+h)*80 + d)][l]     (no act, transposed)
template <int MODE>
__global__ void k_proj(const bf16* __restrict__ X, const bf16* __restrict__ WT,
                       const float* __restrict__ bias, bf16* __restrict__ out) {
  __shared__ bf16 As[128 * 64];
  __shared__ bf16 Bs[128 * 64];
  const int tid = threadIdx.x, lane = tid & 63, wid = tid >> 6;
  const int wr = wid >> 1, wc = wid & 1;
  const int lr = lane & 15, lk = lane >> 4;
  const int n0 = blockIdx.x * 128, c0 = blockIdx.y * 128;
  f32x4 acc[4][4] = {};

  for (int ks = 0; ks < 16; ++ks) {
    const int k0 = ks * 64;
    __syncthreads();
    stage128(As, X + (size_t)n0 * DIM + k0, DIM, wid, lane);
    stage128(Bs, WT + (size_t)c0 * DIM + k0, DIM, wid, lane);
    __syncthreads();
#pragma unroll
    for (int kk = 0; kk < 2; ++kk) {
      bf16x8 af[4], bfr[4];
#pragma unroll
      for (int rb = 0; rb < 4; ++rb)
        af[rb] = *reinterpret_cast<const bf16x8*>(&As[(wr * 64 + rb * 16 + lr) * 64 + kk * 32 + lk * 8]);
#pragma unroll
      for (int cb = 0; cb < 4; ++cb)
        bfr[cb] = *reinterpret_cast<const bf16x8*>(&Bs[(wc * 64 + cb * 16 + lr) * 64 + kk * 32 + lk * 8]);
#pragma unroll
      for (int rb = 0; rb < 4; ++rb)
#pragma unroll
        for (int cb = 0; cb < 4; ++cb)
          acc[rb][cb] = MFMA_(af[rb], bfr[cb], acc[rb][cb]);
    }
  }

  // epilogue
  float bvv[4];
#pragma unroll
  for (int cb = 0; cb < 4; ++cb) bvv[cb] = bias[c0 + wc * 64 + cb * 16 + lr];
  const int bidx = n0 >> 12;           // batch
  const int l0 = n0 & (LSEQ - 1);
#pragma unroll
  for (int rb = 0; rb < 4; ++rb) {
#pragma unroll
    for (int cb = 0; cb < 4; ++cb) {
      const int c = c0 + wc * 64 + cb * 16 + lr;
      if (MODE == 0) {
#pragma unroll
        for (int r = 0; r < 4; ++r) {
          float x = acc[rb][cb][r] + bvv[cb];
          x = fmaxf(x, 0.f) + EPSF;
          const int row = n0 + wr * 64 + rb * 16 + lk * 4 + r;
          out[(size_t)row * DIM + c] = (bf16)x;
        }
      } else {
        const int l = l0 + wr * 64 + rb * 16 + lk * 4;
        bf16x4 o;
#pragma unroll
        for (int r = 0; r < 4; ++r) {
          float x = acc[rb][cb][r] + bvv[cb];
          if (MODE == 1) x = fmaxf(x, 0.f) + EPSF;
          o[r] = (bf16)x;
        }
        size_t rowbase;
        if (MODE == 1) rowbase = (size_t)bidx * 1024 + c;                          // kt [b][c][L]
        else           rowbase = ((size_t)(bidx * HH + (c >> 6)) * 80 + (c & 63)); // vt [b][h][80][L]
        *reinterpret_cast<bf16x4*>(out + rowbase * LSEQ + l) = o;
      }
    }
  }
}

// ---------------- kvs: per (b,h) C[64 m][80 d'] = kt . vt^T over l ---------
__global__ __launch_bounds__(256, 2) void k_kvs(const bf16* __restrict__ kt,
                                                const bf16* __restrict__ vt,
                                                float* __restrict__ kvs) {
  const int tid = threadIdx.x, lane = tid & 63, wid = tid >> 6;
  const int lr = lane & 15, lk = lane >> 4;
  const int bh = blockIdx.y;
  const int lbase = blockIdx.x * 1024;
  __shared__ bf16 As[64][64];   // kt tile
  __shared__ bf16 Bs[80][64];   // vt tile (incl ones row)
  f32x4 acc[5] = {};
  const bf16* ktb = kt + (size_t)bh * 64 * LSEQ;
  const bf16* vtb = vt + (size_t)bh * 80 * LSEQ;

  for (int ks = 0; ks < 16; ++ks) {
    const int l0 = lbase + ks * 64;
    __syncthreads();
#pragma unroll
    for (int i = 0; i < 2; ++i) {   // A: 4096 elems
      const int e = i * 2048 + tid * 8;
      const int row = e >> 6, col = e & 63;
      *reinterpret_cast<bf16x8*>(&As[row][col]) =
          *reinterpret_cast<const bf16x8*>(ktb + (size_t)row * LSEQ + l0 + col);
    }
#pragma unroll
    for (int i = 0; i < 2; ++i) {   // B: first 4096 of 5120
      const int e = i * 2048 + tid * 8;
      const int row = e >> 6, col = e & 63;
      *reinterpret_cast<bf16x8*>(&Bs[row][col]) =
          *reinterpret_cast<const bf16x8*>(vtb + (size_t)row * LSEQ + l0 + col);
    }
    if (tid < 128) {                // B: rows 64..79
      const int e = 4096 + tid * 8;
      const int row = e >> 6, col = e & 63;
      *reinterpret_cast<bf16x8*>(&Bs[row][col]) =
          *reinterpret_cast<const bf16x8*>(vtb + (size_t)row * LSEQ + l0 + col);
    }
    __syncthreads();
#pragma unroll
    for (int kk = 0; kk < 2; ++kk) {
      const bf16x8 af = *reinterpret_cast<const bf16x8*>(&As[wid * 16 + lr][kk * 32 + lk * 8]);
#pragma unroll
      for (int cb = 0; cb < 5; ++cb) {
        const bf16x8 bfr = *reinterpret_cast<const bf16x8*>(&Bs[cb * 16 + lr][kk * 32 + lk * 8]);
        acc[cb] = MFMA_(af, bfr, acc[cb]);
      }
    }
  }
  float* kb = kvs + (size_t)bh * 64 * 80;
#pragma unroll
  for (int cb = 0; cb < 5; ++cb) {
    const int dcol = cb * 16 + lr;
#pragma unroll
    for (int r = 0; r < 4; ++r) {
      const int m = wid * 16 + lk * 4 + r;
      atomicAdd(kb + m * 80 + dcol, acc[cb][r]);
    }
  }
}

// ---------------- kvs fp32 [bh][64][80] -> bav bf16 [bh][80][64] -----------
__global__ void k_kvs_t(const float* __restrict__ kvs, bf16* __restrict__ bav) {
  const int bh = blockIdx.x;
  const float* src = kvs + (size_t)bh * 5120;
  bf16* dst = bav + (size_t)bh * 5120;
  for (int i = threadIdx.x; i < 5120; i += 256) {
    const int dp = i >> 6, mm = i & 63;
    dst[i] = (bf16)src[mm * 80 + dp];
  }
}

// ---------------- av: per (b,h) C[128 l][80] = q . bav^T; normalize --------
__global__ __launch_bounds__(256, 2) void k_av(const bf16* __restrict__ q,
                                               const bf16* __restrict__ bav,
                                               bf16* __restrict__ avn) {
  const int tid = threadIdx.x, lane = tid & 63, wid = tid >> 6;
  const int lr = lane & 15, lk = lane >> 4;
  const int bh = blockIdx.y, b = bh >> 4, h = bh & 15;
  const int l0 = blockIdx.x * 128;
  __shared__ bf16 As[128][64];
  __shared__ bf16 Bs[80][64];
  __shared__ float nrm[128];

  const bf16* qb = q + ((size_t)b * LSEQ + l0) * DIM + h * 64;
#pragma unroll
  for (int i = 0; i < 4; ++i) {
    const int e = i * 2048 + tid * 8;
    const int row = e >> 6, col = e & 63;
    *reinterpret_cast<bf16x8*>(&As[row][col]) =
        *reinterpret_cast<const bf16x8*>(qb + (size_t)row * DIM + col);
  }
  const bf16* bb = bav + (size_t)bh * 5120;
#pragma unroll
  for (int i = 0; i < 2; ++i) {
    const int e = i * 2048 + tid * 8;
    const int row = e >> 6, col = e & 63;
    *reinterpret_cast<bf16x8*>(&Bs[row][col]) =
        *reinterpret_cast<const bf16x8*>(bb + row * 64 + col);
  }
  if (tid < 128) {
    const int e = 4096 + tid * 8;
    const int row = e >> 6, col = e & 63;
    *reinterpret_cast<bf16x8*>(&Bs[row][col]) =
        *reinterpret_cast<const bf16x8*>(bb + row * 64 + col);
  }
  __syncthreads();

  f32x4 acc[2][5] = {};
#pragma unroll
  for (int kk = 0; kk < 2; ++kk) {
    bf16x8 af[2];
    af[0] = *reinterpret_cast<const bf16x8*>(&As[wid * 32 + lr][kk * 32 + lk * 8]);
    af[1] = *reinterpret_cast<const bf16x8*>(&As[wid * 32 + 16 + lr][kk * 32 + lk * 8]);
#pragma unroll
    for (int cb = 0; cb < 5; ++cb) {
      const bf16x8 bfr = *reinterpret_cast<const bf16x8*>(&Bs[cb * 16 + lr][kk * 32 + lk * 8]);
      acc[0][cb] = MFMA_(af[0], bfr, acc[0][cb]);
      acc[1][cb] = MFMA_(af[1], bfr, acc[1][cb]);
    }
  }
  if (lr == 0) {
#pragma unroll
    for (int rb = 0; rb < 2; ++rb)
#pragma unroll
      for (int r = 0; r < 4; ++r)
        nrm[wid * 32 + rb * 16 + lk * 4 + r] = acc[rb][4][r];
  }
  __syncthreads();
  bf16* ob = avn + ((size_t)b * LSEQ + l0) * DIM + h * 64;
#pragma unroll
  for (int rb = 0; rb < 2; ++rb) {
#pragma unroll
    for (int cb = 0; cb < 4; ++cb) {
#pragma unroll
      for (int r = 0; r < 4; ++r) {
        const int row = wid * 32 + rb * 16 + lk * 4 + r;
        const float x = acc[rb][cb][r] / nrm[row];
        ob[(size_t)row * DIM + cb * 16 + lr] = (bf16)x;
      }
    }
  }
}

// ---------------- out: out = avn . WoT^T + bo   (fp32) ---------------------
__global__ void k_out(const bf16* __restrict__ A, const bf16* __restrict__ WoT,
                      const float* __restrict__ bo, float* __restrict__ out) {
  __shared__ bf16 As[128 * 64];
  __shared__ bf16 Bs[128 * 64];
  const int tid = threadIdx.x, lane = tid & 63, wid = tid >> 6;
  const int wr = wid >> 1, wc = wid & 1;
  const int lr = lane & 15, lk = lane >> 4;
  const int n0 = blockIdx.x * 128, c0 = blockIdx.y * 128;
  f32x4 acc[4][4] = {};

  for (int ks = 0; ks < 16; ++ks) {
    const int k0 = ks * 64;
    __syncthreads();
    stage128(As, A + (size_t)n0 * DIM + k0, DIM, wid, lane);
    stage128(Bs, WoT + (size_t)c0 * DIM + k0, DIM, wid, lane);
    __syncthreads();
#pragma unroll
    for (int kk = 0; kk < 2; ++kk) {
      bf16x8 af[4], bfr[4];
#pragma unroll
      for (int rb = 0; rb < 4; ++rb)
        af[rb] = *reinterpret_cast<const bf16x8*>(&As[(wr * 64 + rb * 16 + lr) * 64 + kk * 32 + lk * 8]);
#pragma unroll
      for (int cb = 0; cb < 4; ++cb)
        bfr[cb] = *reinterpret_cast<const bf16x8*>(&Bs[(wc * 64 + cb * 16 + lr) * 64 + kk * 32 + lk * 8]);
#pragma unroll
      for (int rb = 0; rb < 4; ++rb)
#pragma unroll
        for (int cb = 0; cb < 4; ++cb)
          acc[rb][cb] = MFMA_(af[rb], bfr[cb], acc[rb][cb]);
    }
  }
  float bvv[4];
#pragma unroll
  for (int cb = 0; cb < 4; ++cb) bvv[cb] = bo[c0 + wc * 64 + cb * 16 + lr];
#pragma unroll
  for (int rb = 0; rb < 4; ++rb)
#pragma unroll
    for (int cb = 0; cb < 4; ++cb)
#pragma unroll
      for (int r = 0; r < 4; ++r) {
        const int row = n0 + wr * 64 + rb * 16 + lk * 4 + r;
        const int c = c0 + wc * 64 + cb * 16 + lr;
        out[(size_t)row * DIM + c] = acc[rb][cb][r] + bvv[cb];
      }
}

// ---------------------------------------------------------------------------
extern "C" void kernel_launch(void* const* d_in, const int* in_sizes, int n_in,
                              void* d_out, int out_size, void* d_ws, size_t ws_size,
                              hipStream_t stream) {
  const float* query = (const float*)d_in[0];
  const float* key   = (const float*)d_in[1];
  const float* value = (const float*)d_in[2];
  const float* Wq    = (const float*)d_in[3];
  const float* bq    = (const float*)d_in[4];
  const float* Wk    = (const float*)d_in[5];
  const float* bk    = (const float*)d_in[6];
  const float* Wv    = (const float*)d_in[7];
  const float* bvp   = (const float*)d_in[8];
  const float* Wo    = (const float*)d_in[9];
  const float* bo    = (const float*)d_in[10];
  float* out = (float*)d_out;
  char* ws = (char*)d_ws;

  // workspace layout (bytes); XB regions are reused once dead:
  //   KT = XBv, Qb = XBk, AV = XBq  (projection order v -> k -> q)
  const size_t off_wqt = 0;                        // 2 MB each
  const size_t off_wkt = off_wqt + (2u << 20);
  const size_t off_wvt = off_wkt + (2u << 20);
  const size_t off_wot = off_wvt + (2u << 20);
  const size_t off_xb  = off_wot + (2u << 20);     // 3 x 33,554,432
  const size_t off_vt  = off_xb  + 100663296ull;   // 41,943,040
  const size_t off_kvs = off_vt  + 41943040ull;    //  1,310,720 (fp32)
  const size_t off_bav = off_kvs + 1310720ull;     //    655,360
  const size_t total   = off_bav + 655360ull;      // ~146 MB
  if (ws_size < total) return;

  bf16*  WQT = (bf16*)(ws + off_wqt);
  bf16*  WKT = (bf16*)(ws + off_wkt);
  bf16*  WVT = (bf16*)(ws + off_wvt);
  bf16*  WOT = (bf16*)(ws + off_wot);
  bf16*  XB  = (bf16*)(ws + off_xb);
  bf16*  XBq = XB;
  bf16*  XBk = XB + 16777216u;
  bf16*  XBv = XB + 33554432u;
  bf16*  VT  = (bf16*)(ws + off_vt);
  float* KVS = (float*)(ws + off_kvs);
  bf16*  BAV = (bf16*)(ws + off_bav);
  // aliases (regions dead before reuse):
  bf16*  KT  = XBv;   // written by k_proj<1>, after XBv last read (k_proj<2>)
  bf16*  Qb  = XBk;   // written by k_proj<0>, after XBk last read (k_proj<1>)
  bf16*  AV  = XBq;   // written by k_av,      after XBq last read (k_proj<0>)

  // prep
  k_cvt<<<dim3(8192, 3), 256, 0, stream>>>(query, key, value, XB);
  k_prep_w4<<<dim3(32, 32, 4), 256, 0, stream>>>(Wq, Wk, Wv, Wo, WQT, WKT, WVT, WOT);
  k_init_vt<<<16384, 256, 0, stream>>>(VT);
  hipMemsetAsync(KVS, 0, 1310720ull, stream);

  // projections (order matters for aliasing: v, then k, then q)
  k_proj<2><<<dim3(128, 8), 256, 0, stream>>>(XBv, WVT, bvp, VT);
  k_proj<1><<<dim3(128, 8), 256, 0, stream>>>(XBk, WKT, bk, KT);
  k_proj<0><<<dim3(128, 8), 256, 0, stream>>>(XBq, WQT, bq, Qb);

  // state + normalizer
  k_kvs<<<dim3(4, 64), 256, 0, stream>>>(KT, VT, KVS);
  k_kvs_t<<<64, 256, 0, stream>>>(KVS, BAV);

  // attention readout + normalization
  k_av<<<dim3(32, 64), 256, 0, stream>>>(Qb, BAV, AV);

  // output projection
  k_out<<<dim3(128, 8), 256, 0, stream>>>(AV, WOT, bo, out);
}

// Round 4
// 280.187 us; speedup vs baseline: 1.2394x; 1.0157x over previous
//
#include <hip/hip_runtime.h>
#include <stdint.h>

// ---------------------------------------------------------------------------
// Linear (kernelized) attention, B=4 L=4096 D=1024 H=16 M=64, fp32 in/out.
//   1. k_cvt    : q/k/v fp32 -> bf16 XB[3][16384][1024] (grid-stride, NT loads)
//   2. k_prep_w4: 4 weight transposes -> bf16 WT[out][in] (MFMA B layout)
//   3. k_proj   : m97-style 128x128/BK=64 MFMA GEMM, global_load_lds x16 both
//                 operands.  MODE 0: q=relu(X Wq+b)+eps -> [B][L][1024]
//                 MODE 1: k -> kt [B][1024][L] (transposed)
//                 MODE 2: v -> vt [B][16][80][L] rows 0..63
//      k_init_vt: vt row 64 = 1.0 (kvs col 64 = ks_sum), 65..79 = 0
//   4. k_kvs    : per (b,h) kvs[64 m][80 d'] += kt . vt^T  (fp32 atomics)
//   5. k_kvs_t  : kvs fp32 -> bav bf16 [bh][80][64] (transpose)
//   6. k_av     : C[l][80] = q . bav^T; col 64 = norm; avn = C/norm (bf16)
//   7. k_out    : out = avn . WoT + bo (fp32), m97-style GEMM
// Workspace aliasing: projections run v->k->q; KT=XBv, Qb=XBk, AV=XBq.
// ---------------------------------------------------------------------------

typedef __bf16 bf16;
typedef __bf16 bf16x4 __attribute__((ext_vector_type(4)));
typedef __bf16 bf16x8 __attribute__((ext_vector_type(8)));
typedef float f32x4 __attribute__((ext_vector_type(4)));

#define MFMA_(a, b, c) __builtin_amdgcn_mfma_f32_16x16x32_bf16((a), (b), (c), 0, 0, 0)

static constexpr int BB   = 4;
static constexpr int LSEQ = 4096;
static constexpr int DIM  = 1024;   // D == H*M
static constexpr int HH   = 16;
static constexpr float EPSF = 0.001f;

// ---- async global->LDS, 16B per lane, wave-uniform LDS base ---------------
__device__ __forceinline__ void gload16(bf16* lds, const bf16* g) {
  __builtin_amdgcn_global_load_lds(
      (const __attribute__((address_space(1))) void*)g,
      (__attribute__((address_space(3))) void*)lds, 16, 0, 0);
}

// stage a 128x64 bf16 tile from row-major src (pre-offset to tile origin).
__device__ __forceinline__ void stage128(bf16* lds, const bf16* src, size_t ld,
                                         int wid, int lane) {
#pragma unroll
  for (int j = 0; j < 4; ++j) {
    const int chunk = wid * 4 + j;
    const int e = chunk * 512 + lane * 8;
    gload16(lds + chunk * 512, src + (size_t)(e >> 6) * ld + (e & 63));
  }
}

// ---------------- q/k/v fp32 -> bf16 (grid-stride, NT input loads) ---------
__global__ void k_cvt(const float* __restrict__ q, const float* __restrict__ k,
                      const float* __restrict__ v, bf16* __restrict__ xb) {
  // 3 tensors x 2^24 elems, processed as bf16x8 chunks: 3 x 2^21 chunks.
  const int nchunk = 3 << 21;
  const int stride = gridDim.x * blockDim.x;
  for (int c = blockIdx.x * blockDim.x + threadIdx.x; c < nchunk; c += stride) {
    const int t = c >> 21;                       // wave-uniform (2^21 % 64 == 0)
    const size_t off = (size_t)(c & ((1 << 21) - 1)) * 8;
    const float* src = (t == 0) ? q : (t == 1) ? k : v;
    const f32x4* sp = reinterpret_cast<const f32x4*>(src + off);
    const f32x4 a = __builtin_nontemporal_load(sp);
    const f32x4 b = __builtin_nontemporal_load(sp + 1);
    bf16x8 o;
    o[0] = (bf16)a[0]; o[1] = (bf16)a[1]; o[2] = (bf16)a[2]; o[3] = (bf16)a[3];
    o[4] = (bf16)b[0]; o[5] = (bf16)b[1]; o[6] = (bf16)b[2]; o[7] = (bf16)b[3];
    *reinterpret_cast<bf16x8*>(xb + (size_t)t * 16777216u + off) = o;
  }
}

// ---------------- weight transpose: fp32 [1024][1024] -> bf16 out[c][r] ----
__global__ void k_prep_w4(const float* __restrict__ W0, const float* __restrict__ W1,
                          const float* __restrict__ W2, const float* __restrict__ W3,
                          bf16* __restrict__ T0, bf16* __restrict__ T1,
                          bf16* __restrict__ T2, bf16* __restrict__ T3) {
  const float* W; bf16* T;
  switch (blockIdx.z) {
    case 0:  W = W0; T = T0; break;
    case 1:  W = W1; T = T1; break;
    case 2:  W = W2; T = T2; break;
    default: W = W3; T = T3; break;
  }
  __shared__ float t[32][33];
  const int tx = threadIdx.x & 31, ty = threadIdx.x >> 5;   // 32 x 8
  const int r0 = blockIdx.x * 32, c0 = blockIdx.y * 32;
#pragma unroll
  for (int j = 0; j < 32; j += 8)
    t[ty + j][tx] = W[(size_t)(r0 + ty + j) * DIM + c0 + tx];
  __syncthreads();
#pragma unroll
  for (int j = 0; j < 32; j += 8)
    T[(size_t)(c0 + ty + j) * DIM + r0 + tx] = (bf16)t[tx][ty + j];
}

// ---------------- vt rows 64..79: row 64 = ones, rest zeros ----------------
__global__ void k_init_vt(bf16* __restrict__ vt) {
  // 64 bh x 16 rows x 4096 = 4,194,304 bf16 = 524,288 bf16x8 chunks
  const int c = blockIdx.x * 256 + threadIdx.x;
  const int l8 = c & 511;
  const int r  = (c >> 9) & 15;
  const int bh = c >> 13;
  const bf16 val = (r == 0) ? (bf16)1.0f : (bf16)0.0f;
  bf16x8 o;
#pragma unroll
  for (int j = 0; j < 8; ++j) o[j] = val;
  *reinterpret_cast<bf16x8*>(vt + ((size_t)bh * 80 + 64 + r) * LSEQ + l8 * 8) = o;
}

// ---------------- projection GEMM: C = act(X . WT^T + bias) ----------------
// MODE 0: q  -> out[n][c]                     (relu + eps)
// MODE 1: k  -> out[(b*1024 + c)][l]          (relu + eps, transposed)
// MODE 2: v  -> out[((b*16+h)*80 + d)][l]     (no act, transposed)
template <int MODE>
__global__ void k_proj(const bf16* __restrict__ X, const bf16* __restrict__ WT,
                       const float* __restrict__ bias, bf16* __restrict__ out) {
  __shared__ bf16 As[128 * 64];
  __shared__ bf16 Bs[128 * 64];
  const int tid = threadIdx.x, lane = tid & 63, wid = tid >> 6;
  const int wr = wid >> 1, wc = wid & 1;
  const int lr = lane & 15, lk = lane >> 4;
  const int n0 = blockIdx.x * 128, c0 = blockIdx.y * 128;
  f32x4 acc[4][4] = {};

  for (int ks = 0; ks < 16; ++ks) {
    const int k0 = ks * 64;
    __syncthreads();
    stage128(As, X + (size_t)n0 * DIM + k0, DIM, wid, lane);
    stage128(Bs, WT + (size_t)c0 * DIM + k0, DIM, wid, lane);
    __syncthreads();
#pragma unroll
    for (int kk = 0; kk < 2; ++kk) {
      bf16x8 af[4], bfr[4];
#pragma unroll
      for (int rb = 0; rb < 4; ++rb)
        af[rb] = *reinterpret_cast<const bf16x8*>(&As[(wr * 64 + rb * 16 + lr) * 64 + kk * 32 + lk * 8]);
#pragma unroll
      for (int cb = 0; cb < 4; ++cb)
        bfr[cb] = *reinterpret_cast<const bf16x8*>(&Bs[(wc * 64 + cb * 16 + lr) * 64 + kk * 32 + lk * 8]);
#pragma unroll
      for (int rb = 0; rb < 4; ++rb)
#pragma unroll
        for (int cb = 0; cb < 4; ++cb)
          acc[rb][cb] = MFMA_(af[rb], bfr[cb], acc[rb][cb]);
    }
  }

  // epilogue
  float bvv[4];
#pragma unroll
  for (int cb = 0; cb < 4; ++cb) bvv[cb] = bias[c0 + wc * 64 + cb * 16 + lr];
  const int bidx = n0 >> 12;           // batch
  const int l0 = n0 & (LSEQ - 1);
#pragma unroll
  for (int rb = 0; rb < 4; ++rb) {
#pragma unroll
    for (int cb = 0; cb < 4; ++cb) {
      const int c = c0 + wc * 64 + cb * 16 + lr;
      if (MODE == 0) {
#pragma unroll
        for (int r = 0; r < 4; ++r) {
          float x = acc[rb][cb][r] + bvv[cb];
          x = fmaxf(x, 0.f) + EPSF;
          const int row = n0 + wr * 64 + rb * 16 + lk * 4 + r;
          out[(size_t)row * DIM + c] = (bf16)x;
        }
      } else {
        const int l = l0 + wr * 64 + rb * 16 + lk * 4;
        bf16x4 o;
#pragma unroll
        for (int r = 0; r < 4; ++r) {
          float x = acc[rb][cb][r] + bvv[cb];
          if (MODE == 1) x = fmaxf(x, 0.f) + EPSF;
          o[r] = (bf16)x;
        }
        size_t rowbase;
        if (MODE == 1) rowbase = (size_t)bidx * 1024 + c;                          // kt [b][c][L]
        else           rowbase = ((size_t)(bidx * HH + (c >> 6)) * 80 + (c & 63)); // vt [b][h][80][L]
        *reinterpret_cast<bf16x4*>(out + rowbase * LSEQ + l) = o;
      }
    }
  }
}

// ---------------- kvs: per (b,h) C[64 m][80 d'] = kt . vt^T over l ---------
__global__ __launch_bounds__(256, 2) void k_kvs(const bf16* __restrict__ kt,
                                                const bf16* __restrict__ vt,
                                                float* __restrict__ kvs) {
  const int tid = threadIdx.x, lane = tid & 63, wid = tid >> 6;
  const int lr = lane & 15, lk = lane >> 4;
  const int bh = blockIdx.y;
  const int lbase = blockIdx.x * 512;       // 8 l-slices of 512
  __shared__ bf16 As[64][64];   // kt tile
  __shared__ bf16 Bs[80][64];   // vt tile (incl ones row)
  f32x4 acc[5] = {};
  const bf16* ktb = kt + (size_t)bh * 64 * LSEQ;
  const bf16* vtb = vt + (size_t)bh * 80 * LSEQ;

  for (int ks = 0; ks < 8; ++ks) {
    const int l0 = lbase + ks * 64;
    __syncthreads();
#pragma unroll
    for (int i = 0; i < 2; ++i) {   // A: 4096 elems
      const int e = i * 2048 + tid * 8;
      const int row = e >> 6, col = e & 63;
      *reinterpret_cast<bf16x8*>(&As[row][col]) =
          *reinterpret_cast<const bf16x8*>(ktb + (size_t)row * LSEQ + l0 + col);
    }
#pragma unroll
    for (int i = 0; i < 2; ++i) {   // B: first 4096 of 5120
      const int e = i * 2048 + tid * 8;
      const int row = e >> 6, col = e & 63;
      *reinterpret_cast<bf16x8*>(&Bs[row][col]) =
          *reinterpret_cast<const bf16x8*>(vtb + (size_t)row * LSEQ + l0 + col);
    }
    if (tid < 128) {                // B: rows 64..79
      const int e = 4096 + tid * 8;
      const int row = e >> 6, col = e & 63;
      *reinterpret_cast<bf16x8*>(&Bs[row][col]) =
          *reinterpret_cast<const bf16x8*>(vtb + (size_t)row * LSEQ + l0 + col);
    }
    __syncthreads();
#pragma unroll
    for (int kk = 0; kk < 2; ++kk) {
      const bf16x8 af = *reinterpret_cast<const bf16x8*>(&As[wid * 16 + lr][kk * 32 + lk * 8]);
#pragma unroll
      for (int cb = 0; cb < 5; ++cb) {
        const bf16x8 bfr = *reinterpret_cast<const bf16x8*>(&Bs[cb * 16 + lr][kk * 32 + lk * 8]);
        acc[cb] = MFMA_(af, bfr, acc[cb]);
      }
    }
  }
  float* kb = kvs + (size_t)bh * 64 * 80;
#pragma unroll
  for (int cb = 0; cb < 5; ++cb) {
    const int dcol = cb * 16 + lr;
#pragma unroll
    for (int r = 0; r < 4; ++r) {
      const int m = wid * 16 + lk * 4 + r;
      atomicAdd(kb + m * 80 + dcol, acc[cb][r]);
    }
  }
}

// ---------------- kvs fp32 [bh][64][80] -> bav bf16 [bh][80][64] -----------
__global__ void k_kvs_t(const float* __restrict__ kvs, bf16* __restrict__ bav) {
  const int bh = blockIdx.x;
  const float* src = kvs + (size_t)bh * 5120;
  bf16* dst = bav + (size_t)bh * 5120;
  for (int i = threadIdx.x; i < 5120; i += 256) {
    const int dp = i >> 6, mm = i & 63;
    dst[i] = (bf16)src[mm * 80 + dp];
  }
}

// ---------------- av: per (b,h) C[128 l][80] = q . bav^T; normalize --------
__global__ __launch_bounds__(256, 2) void k_av(const bf16* __restrict__ q,
                                               const bf16* __restrict__ bav,
                                               bf16* __restrict__ avn) {
  const int tid = threadIdx.x, lane = tid & 63, wid = tid >> 6;
  const int lr = lane & 15, lk = lane >> 4;
  const int bh = blockIdx.y, b = bh >> 4, h = bh & 15;
  const int l0 = blockIdx.x * 128;
  __shared__ bf16 As[128][64];
  __shared__ bf16 Bs[80][64];
  __shared__ float nrm[128];

  const bf16* qb = q + ((size_t)b * LSEQ + l0) * DIM + h * 64;
#pragma unroll
  for (int i = 0; i < 4; ++i) {
    const int e = i * 2048 + tid * 8;
    const int row = e >> 6, col = e & 63;
    *reinterpret_cast<bf16x8*>(&As[row][col]) =
        *reinterpret_cast<const bf16x8*>(qb + (size_t)row * DIM + col);
  }
  const bf16* bb = bav + (size_t)bh * 5120;
#pragma unroll
  for (int i = 0; i < 2; ++i) {
    const int e = i * 2048 + tid * 8;
    const int row = e >> 6, col = e & 63;
    *reinterpret_cast<bf16x8*>(&Bs[row][col]) =
        *reinterpret_cast<const bf16x8*>(bb + row * 64 + col);
  }
  if (tid < 128) {
    const int e = 4096 + tid * 8;
    const int row = e >> 6, col = e & 63;
    *reinterpret_cast<bf16x8*>(&Bs[row][col]) =
        *reinterpret_cast<const bf16x8*>(bb + row * 64 + col);
  }
  __syncthreads();

  f32x4 acc[2][5] = {};
#pragma unroll
  for (int kk = 0; kk < 2; ++kk) {
    bf16x8 af[2];
    af[0] = *reinterpret_cast<const bf16x8*>(&As[wid * 32 + lr][kk * 32 + lk * 8]);
    af[1] = *reinterpret_cast<const bf16x8*>(&As[wid * 32 + 16 + lr][kk * 32 + lk * 8]);
#pragma unroll
    for (int cb = 0; cb < 5; ++cb) {
      const bf16x8 bfr = *reinterpret_cast<const bf16x8*>(&Bs[cb * 16 + lr][kk * 32 + lk * 8]);
      acc[0][cb] = MFMA_(af[0], bfr, acc[0][cb]);
      acc[1][cb] = MFMA_(af[1], bfr, acc[1][cb]);
    }
  }
  if (lr == 0) {
#pragma unroll
    for (int rb = 0; rb < 2; ++rb)
#pragma unroll
      for (int r = 0; r < 4; ++r)
        nrm[wid * 32 + rb * 16 + lk * 4 + r] = acc[rb][4][r];
  }
  __syncthreads();
  bf16* ob = avn + ((size_t)b * LSEQ + l0) * DIM + h * 64;
#pragma unroll
  for (int rb = 0; rb < 2; ++rb) {
#pragma unroll
    for (int cb = 0; cb < 4; ++cb) {
#pragma unroll
      for (int r = 0; r < 4; ++r) {
        const int row = wid * 32 + rb * 16 + lk * 4 + r;
        const float x = acc[rb][cb][r] / nrm[row];
        ob[(size_t)row * DIM + cb * 16 + lr] = (bf16)x;
      }
    }
  }
}

// ---------------- out: out = avn . WoT^T + bo   (fp32) ---------------------
__global__ void k_out(const bf16* __restrict__ A, const bf16* __restrict__ WoT,
                      const float* __restrict__ bo, float* __restrict__ out) {
  __shared__ bf16 As[128 * 64];
  __shared__ bf16 Bs[128 * 64];
  const int tid = threadIdx.x, lane = tid & 63, wid = tid >> 6;
  const int wr = wid >> 1, wc = wid & 1;
  const int lr = lane & 15, lk = lane >> 4;
  const int n0 = blockIdx.x * 128, c0 = blockIdx.y * 128;
  f32x4 acc[4][4] = {};

  for (int ks = 0; ks < 16; ++ks) {
    const int k0 = ks * 64;
    __syncthreads();
    stage128(As, A + (size_t)n0 * DIM + k0, DIM, wid, lane);
    stage128(Bs, WoT + (size_t)c0 * DIM + k0, DIM, wid, lane);
    __syncthreads();
#pragma unroll
    for (int kk = 0; kk < 2; ++kk) {
      bf16x8 af[4], bfr[4];
#pragma unroll
      for (int rb = 0; rb < 4; ++rb)
        af[rb] = *reinterpret_cast<const bf16x8*>(&As[(wr * 64 + rb * 16 + lr) * 64 + kk * 32 + lk * 8]);
#pragma unroll
      for (int cb = 0; cb < 4; ++cb)
        bfr[cb] = *reinterpret_cast<const bf16x8*>(&Bs[(wc * 64 + cb * 16 + lr) * 64 + kk * 32 + lk * 8]);
#pragma unroll
      for (int rb = 0; rb < 4; ++rb)
#pragma unroll
        for (int cb = 0; cb < 4; ++cb)
          acc[rb][cb] = MFMA_(af[rb], bfr[cb], acc[rb][cb]);
    }
  }
  float bvv[4];
#pragma unroll
  for (int cb = 0; cb < 4; ++cb) bvv[cb] = bo[c0 + wc * 64 + cb * 16 + lr];
#pragma unroll
  for (int rb = 0; rb < 4; ++rb)
#pragma unroll
    for (int cb = 0; cb < 4; ++cb)
#pragma unroll
      for (int r = 0; r < 4; ++r) {
        const int row = n0 + wr * 64 + rb * 16 + lk * 4 + r;
        const int c = c0 + wc * 64 + cb * 16 + lr;
        out[(size_t)row * DIM + c] = acc[rb][cb][r] + bvv[cb];
      }
}

// ---------------------------------------------------------------------------
extern "C" void kernel_launch(void* const* d_in, const int* in_sizes, int n_in,
                              void* d_out, int out_size, void* d_ws, size_t ws_size,
                              hipStream_t stream) {
  const float* query = (const float*)d_in[0];
  const float* key   = (const float*)d_in[1];
  const float* value = (const float*)d_in[2];
  const float* Wq    = (const float*)d_in[3];
  const float* bq    = (const float*)d_in[4];
  const float* Wk    = (const float*)d_in[5];
  const float* bk    = (const float*)d_in[6];
  const float* Wv    = (const float*)d_in[7];
  const float* bvp   = (const float*)d_in[8];
  const float* Wo    = (const float*)d_in[9];
  const float* bo    = (const float*)d_in[10];
  float* out = (float*)d_out;
  char* ws = (char*)d_ws;

  // workspace layout (bytes); XB regions are reused once dead:
  //   KT = XBv, Qb = XBk, AV = XBq  (projection order v -> k -> q)
  const size_t off_wqt = 0;                        // 2 MB each
  const size_t off_wkt = off_wqt + (2u << 20);
  const size_t off_wvt = off_wkt + (2u << 20);
  const size_t off_wot = off_wvt + (2u << 20);
  const size_t off_xb  = off_wot + (2u << 20);     // 3 x 33,554,432
  const size_t off_vt  = off_xb  + 100663296ull;   // 41,943,040
  const size_t off_kvs = off_vt  + 41943040ull;    //  1,310,720 (fp32)
  const size_t off_bav = off_kvs + 1310720ull;     //    655,360
  const size_t total   = off_bav + 655360ull;      // ~146 MB
  if (ws_size < total) return;

  bf16*  WQT = (bf16*)(ws + off_wqt);
  bf16*  WKT = (bf16*)(ws + off_wkt);
  bf16*  WVT = (bf16*)(ws + off_wvt);
  bf16*  WOT = (bf16*)(ws + off_wot);
  bf16*  XB  = (bf16*)(ws + off_xb);
  bf16*  XBq = XB;
  bf16*  XBk = XB + 16777216u;
  bf16*  XBv = XB + 33554432u;
  bf16*  VT  = (bf16*)(ws + off_vt);
  float* KVS = (float*)(ws + off_kvs);
  bf16*  BAV = (bf16*)(ws + off_bav);
  // aliases (regions dead before reuse):
  bf16*  KT  = XBv;   // written by k_proj<1>, after XBv last read (k_proj<2>)
  bf16*  Qb  = XBk;   // written by k_proj<0>, after XBk last read (k_proj<1>)
  bf16*  AV  = XBq;   // written by k_av,      after XBq last read (k_proj<0>)

  // prep
  k_cvt<<<2048, 256, 0, stream>>>(query, key, value, XB);
  k_prep_w4<<<dim3(32, 32, 4), 256, 0, stream>>>(Wq, Wk, Wv, Wo, WQT, WKT, WVT, WOT);
  k_init_vt<<<2048, 256, 0, stream>>>(VT);
  (void)hipMemsetAsync(KVS, 0, 1310720ull, stream);

  // projections (order matters for aliasing: v, then k, then q)
  k_proj<2><<<dim3(128, 8), 256, 0, stream>>>(XBv, WVT, bvp, VT);
  k_proj<1><<<dim3(128, 8), 256, 0, stream>>>(XBk, WKT, bk, KT);
  k_proj<0><<<dim3(128, 8), 256, 0, stream>>>(XBq, WQT, bq, Qb);

  // state + normalizer
  k_kvs<<<dim3(8, 64), 256, 0, stream>>>(KT, VT, KVS);
  k_kvs_t<<<64, 256, 0, stream>>>(KVS, BAV);

  // attention readout + normalization
  k_av<<<dim3(32, 64), 256, 0, stream>>>(Qb, BAV, AV);

  // output projection
  k_out<<<dim3(128, 8), 256, 0, stream>>>(AV, WOT, bo, out);
}